// Round 13
// baseline (200.469 us; speedup 1.0000x reference)
//
#include <hip/hip_runtime.h>
#include <hip/hip_bf16.h>
#include <math.h>

#define B_  2
#define L_  2048
#define D_  2048
#define H_  16
#define HD_ 128
#define EPS_ 1e-5f
#define NT2 32   // K / 64

typedef __attribute__((ext_vector_type(8)))  short short8;
typedef __attribute__((ext_vector_type(4)))  float f32x4;
typedef __attribute__((ext_vector_type(16))) float f32x16;

static __device__ inline unsigned short bfb(float x) {
    __hip_bfloat16 h = __float2bfloat16(x);
    unsigned short s;
    __builtin_memcpy(&s, &h, 2);
    return s;
}
static __device__ inline unsigned pk2(float a, float b) {
    return (unsigned)bfb(a) | ((unsigned)bfb(b) << 16);
}
static __device__ inline float bf2f(unsigned short u) {
    unsigned v = ((unsigned)u) << 16;
    float f;
    __builtin_memcpy(&f, &v, 4);
    return f;
}

// direct-to-LDS 16B copy: LDS dest = wave-uniform base + lane*16
static __device__ __forceinline__ void gld_lds16(const void* g, void* l) {
    __builtin_amdgcn_global_load_lds(
        (const __attribute__((address_space(1))) unsigned int*)g,
        (__attribute__((address_space(3))) unsigned int*)l,
        16, 0, 0);
}

// ---------------------------------------------------------------------------
// fused cast f32 -> bf16 for x, Wq, Wk, Wv (dsts contiguous in ws)
// ---------------------------------------------------------------------------
#define XN4 2097152              // 8388608/4
#define WN4 1048576              // 4194304/4
#define TOT4 (XN4 + 3 * WN4)     // 5242880

__global__ __launch_bounds__(256) void cast4_kernel(
    const float* __restrict__ x,  const float* __restrict__ Wq,
    const float* __restrict__ Wk, const float* __restrict__ Wv,
    __hip_bfloat16* __restrict__ dst)
{
    int i = blockIdx.x * 256 + threadIdx.x;
    const int st = gridDim.x * 256;
    for (; i < TOT4; i += st) {
        const float* s;
        int off;
        if (i < XN4)                { s = x;  off = i; }
        else if (i < XN4 + WN4)     { s = Wq; off = i - XN4; }
        else if (i < XN4 + 2 * WN4) { s = Wk; off = i - XN4 - WN4; }
        else                        { s = Wv; off = i - XN4 - 2 * WN4; }
        float4 v = ((const float4*)s)[off];
        uint2 r;
        r.x = pk2(v.x, v.y);
        r.y = pk2(v.z, v.w);
        ((uint2*)dst)[i] = r;
    }
}

// ---------------------------------------------------------------------------
// Fused projection GEMM — 256x256 tile, 8 waves (2M x 4N), wave tile 128x64
// (acc[8][4] = 128 VGPR), BK=64, 128 KB LDS double-buffered, 4-phase/K-tile
// counted-vmcnt schedule (T2+T3+T4+T5).  Per K-tile, per wave: 24 ds_read_b128
// for 64 MFMA -> MFMA-pipe-bound (LDS 2304 cyc < MFMA 2483 cyc per CU).
// Race-freedom: each STAGE into buf[kt&1] is issued only after the
// lgkmcnt(0)+s_barrier that proves all waves' reads of that region completed;
// vmcnt(8) at tile entry = exactly the next tile's 8 loads stay in flight.
// Grid 384 (16 mt x 24 nt), XCD-chunked nt-major (384%8==0).
// zsel = n0g>>11: Q,K -> [b,h,l,hd] (K also transposed); V -> [b,n,l].
// ---------------------------------------------------------------------------
__global__ __launch_bounds__(512) void proj256(
    const __hip_bfloat16* __restrict__ X,
    const __hip_bfloat16* __restrict__ Wc,
    __hip_bfloat16* __restrict__ Qo, __hip_bfloat16* __restrict__ Ko,
    __hip_bfloat16* __restrict__ VT, __hip_bfloat16* __restrict__ KT)
{
    __shared__ __align__(16) char lds[131072];   // [2] x (A 32K | B 32K)

    const int t  = threadIdx.x;
    const int w  = t >> 6, l = t & 63;
    const int li = l & 15, hi4 = l >> 4;
    const int wm = w >> 2, wn = w & 3;

    const int bid = blockIdx.x;                    // 0..383
    const int wg  = (bid & 7) * 48 + (bid >> 3);   // XCD-chunked (384 % 8 == 0)
    const int nt  = wg >> 4;                       // 0..23  (nt-major per XCD)
    const int mt  = wg & 15;                       // 0..15
    const int m0  = mt * 256;
    const int n0g = nt * 256;

    const int srow = l >> 3;                       // row within 8-row chunk
    const int scol = ((l & 7) ^ (l >> 3)) * 8;     // pre-swizzled source col
    const int swz  = (li & 7) << 4;                // read-side XOR (row&7 == li&7)

    f32x4 acc[8][4];
    #pragma unroll
    for (int i = 0; i < 8; ++i)
        #pragma unroll
        for (int j = 0; j < 4; ++j)
            #pragma unroll
            for (int r = 0; r < 4; ++r) acc[i][j][r] = 0.f;

    auto STAGE_B = [&](int tt) {   // 4 glds: B rows (N) for tile tt
        char* Bb = lds + (tt & 1) * 65536 + 32768;
        const size_t kc = (size_t)(tt * 64) + scol;
        #pragma unroll
        for (int j = 0; j < 4; ++j) {
            const int chunk = w * 4 + j;           // 0..31
            const int row   = chunk * 8 + srow;    // 0..255
            gld_lds16(Wc + (size_t)(n0g + row) * D_ + kc, Bb + chunk * 1024);
        }
    };
    auto STAGE_A = [&](int tt) {   // 4 glds: A rows (M) for tile tt
        char* Ab = lds + (tt & 1) * 65536;
        const size_t kc = (size_t)(tt * 64) + scol;
        #pragma unroll
        for (int j = 0; j < 4; ++j) {
            const int chunk = w * 4 + j;
            const int row   = chunk * 8 + srow;
            gld_lds16(X + (size_t)(m0 + row) * D_ + kc, Ab + chunk * 1024);
        }
    };

    STAGE_B(0); STAGE_A(0); STAGE_B(1); STAGE_A(1);   // 16 loads in flight

    for (int kt = 0; kt < NT2; ++kt) {
        const char* Ab = lds + (kt & 1) * 65536;
        const char* Bb = Ab + 32768;

        // tile entry: this tile's 8 loads landed (next tile's 8 stay in flight)
        if (kt < NT2 - 1) asm volatile("s_waitcnt vmcnt(8)" ::: "memory");
        else              asm volatile("s_waitcnt vmcnt(0)" ::: "memory");
        __builtin_amdgcn_sched_barrier(0);
        __builtin_amdgcn_s_barrier();
        __builtin_amdgcn_sched_barrier(0);

        short8 a[4][2], b[4][2], a2[4][2];
        // P1: 16 ds_reads (a mf0-3, b all) + MFMA kk0 x mf0-3
        #pragma unroll
        for (int mf = 0; mf < 4; ++mf)
            #pragma unroll
            for (int kk = 0; kk < 2; ++kk)
                a[mf][kk] = *(const short8*)(Ab + (wm * 128 + mf * 16 + li) * 128 +
                                             ((kk * 64 + hi4 * 16) ^ swz));
        #pragma unroll
        for (int nf = 0; nf < 4; ++nf)
            #pragma unroll
            for (int kk = 0; kk < 2; ++kk)
                b[nf][kk] = *(const short8*)(Bb + (wn * 64 + nf * 16 + li) * 128 +
                                             ((kk * 64 + hi4 * 16) ^ swz));
        __builtin_amdgcn_s_setprio(1);
        #pragma unroll
        for (int mf = 0; mf < 4; ++mf)
            #pragma unroll
            for (int nf = 0; nf < 4; ++nf)
                acc[mf][nf] = __builtin_amdgcn_mfma_f32_16x16x32_bf16(
                    a[mf][0], b[nf][0], acc[mf][nf], 0, 0, 0);
        __builtin_amdgcn_s_setprio(0);

        // all B-reads (and P1 a-reads) drained chip-wide -> B region free
        asm volatile("s_waitcnt lgkmcnt(0)" ::: "memory");
        __builtin_amdgcn_sched_barrier(0);
        __builtin_amdgcn_s_barrier();
        __builtin_amdgcn_sched_barrier(0);

        // P2: stage B(kt+2) + MFMA kk1 x mf0-3
        if (kt < NT2 - 2) STAGE_B(kt + 2);
        __builtin_amdgcn_s_setprio(1);
        #pragma unroll
        for (int mf = 0; mf < 4; ++mf)
            #pragma unroll
            for (int nf = 0; nf < 4; ++nf)
                acc[mf][nf] = __builtin_amdgcn_mfma_f32_16x16x32_bf16(
                    a[mf][1], b[nf][1], acc[mf][nf], 0, 0, 0);
        __builtin_amdgcn_s_setprio(0);

        // P3: 8 ds_reads (a mf4-7) + MFMA kk0 x mf4-7   (A region still intact)
        #pragma unroll
        for (int mf = 0; mf < 4; ++mf)
            #pragma unroll
            for (int kk = 0; kk < 2; ++kk)
                a2[mf][kk] = *(const short8*)(Ab + (wm * 128 + (mf + 4) * 16 + li) * 128 +
                                              ((kk * 64 + hi4 * 16) ^ swz));
        __builtin_amdgcn_s_setprio(1);
        #pragma unroll
        for (int mf = 0; mf < 4; ++mf)
            #pragma unroll
            for (int nf = 0; nf < 4; ++nf)
                acc[mf + 4][nf] = __builtin_amdgcn_mfma_f32_16x16x32_bf16(
                    a2[mf][0], b[nf][0], acc[mf + 4][nf], 0, 0, 0);
        __builtin_amdgcn_s_setprio(0);

        // all A-reads drained chip-wide -> A region free
        asm volatile("s_waitcnt lgkmcnt(0)" ::: "memory");
        __builtin_amdgcn_sched_barrier(0);
        __builtin_amdgcn_s_barrier();
        __builtin_amdgcn_sched_barrier(0);

        // P4: stage A(kt+2) + MFMA kk1 x mf4-7
        if (kt < NT2 - 2) STAGE_A(kt + 2);
        __builtin_amdgcn_s_setprio(1);
        #pragma unroll
        for (int mf = 0; mf < 4; ++mf)
            #pragma unroll
            for (int nf = 0; nf < 4; ++nf)
                acc[mf + 4][nf] = __builtin_amdgcn_mfma_f32_16x16x32_bf16(
                    a2[mf][1], b[nf][1], acc[mf + 4][nf], 0, 0, 0);
        __builtin_amdgcn_s_setprio(0);
    }

    // epilogue: C[r]: row = hi4*4 + r, col = li (within 16x16 frag)
    const int zsel = n0g >> 11;
    const int np   = n0g & (D_ - 1);
    if (zsel == 2) {
        #pragma unroll
        for (int mf = 0; mf < 8; ++mf) {
            #pragma unroll
            for (int nf = 0; nf < 4; ++nf) {
                const int n     = np + wn * 64 + nf * 16 + li;
                const int mbase = m0 + wm * 128 + mf * 16 + hi4 * 4;
                const int b = mbase >> 11, ml = mbase & (L_ - 1);
                uint2 w2;
                w2.x = pk2(acc[mf][nf][0], acc[mf][nf][1]);
                w2.y = pk2(acc[mf][nf][2], acc[mf][nf][3]);
                *(uint2*)&VT[((size_t)b * D_ + n) * L_ + ml] = w2;
            }
        }
    } else {
        __hip_bfloat16* O = zsel ? Ko : Qo;
        #pragma unroll
        for (int mf = 0; mf < 8; ++mf) {
            #pragma unroll
            for (int nf = 0; nf < 4; ++nf) {
                const int n  = np + wn * 64 + nf * 16 + li;
                const int h  = n >> 7, hd = n & (HD_ - 1);
                #pragma unroll
                for (int r = 0; r < 4; ++r) {
                    const int m = m0 + wm * 128 + mf * 16 + hi4 * 4 + r;
                    const int b = m >> 11, ml = m & (L_ - 1);
                    O[((size_t)(b * H_ + h) * L_ + ml) * HD_ + hd] =
                        __float2bfloat16(acc[mf][nf][r]);
                }
            }
        }
        if (zsel == 1 && KT != nullptr) {
            #pragma unroll
            for (int mf = 0; mf < 8; ++mf) {
                #pragma unroll
                for (int nf = 0; nf < 4; ++nf) {
                    const int n     = np + wn * 64 + nf * 16 + li;
                    const int mbase = m0 + wm * 128 + mf * 16 + hi4 * 4;
                    const int b = mbase >> 11, ml = mbase & (L_ - 1);
                    uint2 w2;
                    w2.x = pk2(acc[mf][nf][0], acc[mf][nf][1]);
                    w2.y = pk2(acc[mf][nf][2], acc[mf][nf][3]);
                    *(uint2*)&KT[((size_t)b * D_ + n) * L_ + ml] = w2;
                }
            }
        }
    }
}

// ---------------------------------------------------------------------------
// State partials: SpT[bh][c][d][k] = sum_{j in chunk c} gamma^(127-j_loc) V[j,d] K[j,k]
// ---------------------------------------------------------------------------
__global__ __launch_bounds__(256) void state_part(
    const __hip_bfloat16* __restrict__ KT, const __hip_bfloat16* __restrict__ VT,
    const float* __restrict__ gl, __hip_bfloat16* __restrict__ SpT)
{
    const int bid = blockIdx.x;       // 512 = c*32 + bh
    const int bh  = bid & 31, c = bid >> 5;
    const int h   = bh & (H_ - 1);
    const int t   = threadIdx.x;
    const int w   = t >> 6, l = t & 63;
    const int li  = l & 31, hi = l >> 5;

    const float gamma = 1.f / (1.f + __expf(-gl[h]));
    const float lg2   = __log2f(gamma);

    __shared__ __align__(16) char Kl[32768];
    __shared__ __align__(16) char Vl[32768];

    const __hip_bfloat16* KTg = KT + (size_t)bh * (HD_ * L_);
    const __hip_bfloat16* VTg = VT + (size_t)bh * (HD_ * L_);
    const int gj = c * 128;
    const int srow4 = l >> 4, sslot = l & 15;

    #pragma unroll
    for (int cc = 0; cc < 8; ++cc) {
        const int ch = w * 8 + cc;
        const int r  = ch * 4 + srow4;
        const int sc = ((sslot ^ (r & 15)) * 8);
        gld_lds16(KTg + (size_t)r * L_ + gj + sc, Kl + ch * 1024);
        gld_lds16(VTg + (size_t)r * L_ + gj + sc, Vl + ch * 1024);
    }
    __syncthreads();

    f32x16 acc[4];
    #pragma unroll
    for (int cch = 0; cch < 4; ++cch)
        #pragma unroll
        for (int r = 0; r < 16; ++r) acc[cch][r] = 0.f;

    #pragma unroll
    for (int s = 0; s < 8; ++s) {
        const int boff = ((s * 2 + hi) ^ (li & 15)) << 4;
        short8 vraw = *(const short8*)(Vl + (w * 32 + li) * 256 + boff);
        short8 af;
        #pragma unroll
        for (int e = 0; e < 8; ++e) {
            const int jl = s * 16 + hi * 8 + e;
            const float f = bf2f((unsigned short)vraw[e]) *
                            exp2f(lg2 * (float)(127 - jl));
            af[e] = (short)bfb(f);
        }
        __builtin_amdgcn_s_setprio(1);
        #pragma unroll
        for (int cch = 0; cch < 4; ++cch) {
            short8 bf = *(const short8*)(Kl + (cch * 32 + li) * 256 + boff);
            acc[cch] = __builtin_amdgcn_mfma_f32_32x32x16_bf16(af, bf, acc[cch], 0, 0, 0);
        }
        __builtin_amdgcn_s_setprio(0);
    }

    __hip_bfloat16* Sp = SpT + (size_t)(bh * 16 + c) * 16384;
    #pragma unroll
    for (int cch = 0; cch < 4; ++cch)
        #pragma unroll
        for (int r = 0; r < 16; ++r) {
            const int d = w * 32 + (r & 3) + 8 * (r >> 2) + 4 * hi;
            Sp[(size_t)d * 128 + cch * 32 + li] = __float2bfloat16(acc[cch][r]);
        }
}

// ---------------------------------------------------------------------------
// State scan: S_c = gamma^128 * S_{c-1} + Sp_c
// ---------------------------------------------------------------------------
__global__ __launch_bounds__(256) void state_scan(
    const __hip_bfloat16* __restrict__ SpT, __hip_bfloat16* __restrict__ SbT,
    const float* __restrict__ gl)
{
    const int bh = blockIdx.x;
    const int h  = bh & (H_ - 1);
    const float gamma = 1.f / (1.f + __expf(-gl[h]));
    const float g128  = exp2f(__log2f(gamma) * 128.f);
    const int fid = blockIdx.y * 256 + threadIdx.x;

    float a0 = 0.f, a1 = 0.f, a2 = 0.f, a3 = 0.f;
    for (int c = 0; c < 16; ++c) {
        const size_t off = (size_t)(bh * 16 + c) * 16384 + (size_t)fid * 4;
        uint2 v = *(const uint2*)(SpT + off);
        a0 = g128 * a0 + bf2f((unsigned short)(v.x & 0xffff));
        a1 = g128 * a1 + bf2f((unsigned short)(v.x >> 16));
        a2 = g128 * a2 + bf2f((unsigned short)(v.y & 0xffff));
        a3 = g128 * a3 + bf2f((unsigned short)(v.y >> 16));
        uint2 o;
        o.x = pk2(a0, a1);
        o.y = pk2(a2, a3);
        *(uint2*)(SbT + off) = o;
    }
}

// ---------------------------------------------------------------------------
// Retention (bf16 MFMA), chunked + fallback, fused GN partials.
// ---------------------------------------------------------------------------
__global__ __launch_bounds__(256) void retn_kernel(
    const __hip_bfloat16* __restrict__ Qb, const __hip_bfloat16* __restrict__ Kb,
    const __hip_bfloat16* __restrict__ VT, const float* __restrict__ gl,
    float* __restrict__ out, float2* __restrict__ part,
    const __hip_bfloat16* __restrict__ SbT, int use_chunks)
{
    const int bid = blockIdx.x;
    const int mm  = bid >> 5;
    const int m   = use_chunks ? mm : ((mm < 8) ? (15 - mm) : (mm - 8));
    const int bh  = bid & 31;
    const int b   = bh >> 4, h = bh & (H_ - 1);
    const int t   = threadIdx.x;
    const int w   = t >> 6, l = t & 63;
    const int li  = l & 31, hi = l >> 5;

    const float gamma = 1.f / (1.f + __expf(-gl[h]));
    const float lg2   = __log2f(gamma);
    const float scale = 0.08838834764831845f;   // 128^-0.5

    __shared__ __align__(16) char Klds[32768];
    __shared__ __align__(16) char Vlds[32768];
    __shared__ float rs[4], rq[4];

    const size_t base = (size_t)bh * (L_ * HD_);
    const __hip_bfloat16* VTg = VT + (size_t)bh * (HD_ * L_);
    const int i0 = m * 128 + w * 32;

    short8 qf[8];
    {
        const __hip_bfloat16* qrow = Qb + base + (size_t)(i0 + li) * HD_;
        #pragma unroll
        for (int s = 0; s < 8; ++s)
            qf[s] = *(const short8*)(qrow + s * 16 + hi * 8);
    }

    float df[16];
    #pragma unroll
    for (int r = 0; r < 16; ++r) {
        const int jl = (r & 3) + 8 * (r >> 2) + 4 * hi;
        df[r] = exp2f(lg2 * (float)(li - jl));
    }

    f32x16 acc[4];
    #pragma unroll
    for (int c = 0; c < 4; ++c)
        #pragma unroll
        for (int r = 0; r < 16; ++r) acc[c][r] = 0.f;

    const int srow4 = l >> 4;
    const int sslot = l & 15;

    if (use_chunks && m > 0) {
        const __hip_bfloat16* Sg = SbT + (size_t)(bh * 16 + (m - 1)) * 16384;
        #pragma unroll
        for (int cc = 0; cc < 8; ++cc) {
            const int ch = w * 8 + cc;
            const int r  = ch * 4 + srow4;
            const int sc = ((sslot ^ (r & 15)) * 8);
            gld_lds16(Sg + (size_t)r * 128 + sc, Klds + ch * 1024);
        }
        __syncthreads();
        #pragma unroll
        for (int s = 0; s < 8; ++s) {
            const int boff = ((s * 2 + hi) ^ (li & 15)) << 4;
            __builtin_amdgcn_s_setprio(1);
            #pragma unroll
            for (int cch = 0; cch < 4; ++cch) {
                short8 sf = *(const short8*)(Klds + (cch * 32 + li) * 256 + boff);
                acc[cch] = __builtin_amdgcn_mfma_f32_32x32x16_bf16(
                    qf[s], sf, acc[cch], 0, 0, 0);
            }
            __builtin_amdgcn_s_setprio(0);
        }
        #pragma unroll
        for (int r = 0; r < 16; ++r) {
            const int il = (r & 3) + 8 * (r >> 2) + 4 * hi + w * 32;
            const float fr = exp2f(lg2 * (float)(il + 1)) * scale;
            acc[0][r] *= fr; acc[1][r] *= fr; acc[2][r] *= fr; acc[3][r] *= fr;
        }
    }

    const int gj0 = use_chunks ? m * 128 : 0;
    for (int gj = gj0; gj <= m * 128; gj += 128) {
        __syncthreads();
        #pragma unroll
        for (int cc = 0; cc < 8; ++cc) {
            const int c  = w * 8 + cc;
            const int r  = c * 4 + srow4;
            const int sc = ((sslot ^ (r & 15)) * 8);
            gld_lds16(Kb + base + (size_t)(gj + r) * HD_ + sc, Klds + c * 1024);
            gld_lds16(VTg + (size_t)r * L_ + gj + sc,          Vlds + c * 1024);
        }
        __syncthreads();

        const int tmax = ((i0 - gj) >> 5) < 3 ? ((i0 - gj) >> 5) : 3;
        for (int jt = 0; jt <= tmax; ++jt) {
            const int j0 = gj + jt * 32;

            f32x16 c;
            #pragma unroll
            for (int r = 0; r < 16; ++r) c[r] = 0.f;
            __builtin_amdgcn_s_setprio(1);
            #pragma unroll
            for (int s = 0; s < 8; ++s) {
                short8 kf = *(const short8*)(Klds + (jt * 32 + li) * 256 +
                                             (((s * 2 + hi) ^ (li & 15)) << 4));
                c = __builtin_amdgcn_mfma_f32_32x32x16_bf16(kf, qf[s], c, 0, 0, 0);
            }
            __builtin_amdgcn_s_setprio(0);

            float p[16];
            const float bt = exp2f(lg2 * (float)(i0 - j0)) * scale;
            if (j0 == i0) {
                #pragma unroll
                for (int r = 0; r < 16; ++r) {
                    const int jl = (r & 3) + 8 * (r >> 2) + 4 * hi;
                    p[r] = (jl <= li) ? c[r] * (df[r] * bt) : 0.f;
                }
            } else {
                #pragma unroll
                for (int r = 0; r < 16; ++r) p[r] = c[r] * (df[r] * bt);
            }

            #pragma unroll
            for (int sl = 0; sl < 2; ++sl) {
                const int o = sl * 8;
                unsigned pk01 = pk2(p[o + 0], p[o + 1]);
                unsigned pk23 = pk2(p[o + 2], p[o + 3]);
                unsigned pk45 = pk2(p[o + 4], p[o + 5]);
                unsigned pk67 = pk2(p[o + 6], p[o + 7]);
                unsigned x01 = (unsigned)__shfl_xor((int)pk01, 32);
                unsigned x23 = (unsigned)__shfl_xor((int)pk23, 32);
                unsigned x45 = (unsigned)__shfl_xor((int)pk45, 32);
                unsigned x67 = (unsigned)__shfl_xor((int)pk67, 32);
                union { short8 v; unsigned u[4]; } pf;
                pf.u[0] = hi ? x45 : pk01;
                pf.u[1] = hi ? x67 : pk23;
                pf.u[2] = hi ? pk45 : x01;
                pf.u[3] = hi ? pk67 : x23;
                __builtin_amdgcn_s_setprio(1);
                #pragma unroll
                for (int cch = 0; cch < 4; ++cch) {
                    short8 vf = *(const short8*)(Vlds + (cch * 32 + li) * 256 +
                                 (((jt * 4 + sl * 2 + hi) ^ (li & 15)) << 4));
                    acc[cch] = __builtin_amdgcn_mfma_f32_32x32x16_bf16(
                        pf.v, vf, acc[cch], 0, 0, 0);
                }
                __builtin_amdgcn_s_setprio(0);
            }
        }
    }

    float s = 0.f, sq = 0.f;
    #pragma unroll
    for (int cch = 0; cch < 4; ++cch) {
        #pragma unroll
        for (int r = 0; r < 16; ++r) {
            const int row = (r & 3) + 8 * (r >> 2) + 4 * hi;
            const float v = acc[cch][r];
            out[(size_t)(b * L_ + i0 + row) * D_ + h * HD_ + cch * 32 + li] = v;
            s += v; sq += v * v;
        }
    }

    #pragma unroll
    for (int off = 32; off > 0; off >>= 1) {
        s  += __shfl_down(s, off);
        sq += __shfl_down(sq, off);
    }
    if (l == 0) { rs[w] = s; rq[w] = sq; }
    __syncthreads();
    if (t == 0)
        part[bh * 16 + m] = make_float2(rs[0] + rs[1] + rs[2] + rs[3],
                                        rq[0] + rq[1] + rq[2] + rq[3]);
}

// ---------------------------------------------------------------------------
// GroupNorm apply (stats partials come fused from retn_kernel)
// ---------------------------------------------------------------------------
__global__ __launch_bounds__(256) void gn_apply(
    float* __restrict__ out, const float2* __restrict__ part,
    const float* __restrict__ gw, const float* __restrict__ gb)
{
    const int bh = blockIdx.x, sl = blockIdx.y;
    const int b = bh >> 4, h = bh & (H_ - 1);
    const int t = threadIdx.x;

    float S = 0.f, SQ = 0.f;
    #pragma unroll
    for (int i = 0; i < 16; ++i) {
        float2 p = part[bh * 16 + i];
        S += p.x; SQ += p.y;
    }
    const float inv  = 1.f / (float)(L_ * HD_);
    const float mean = S * inv;
    float var = SQ * inv - mean * mean;
    if (var < 0.f) var = 0.f;
    const float rstd = rsqrtf(var + EPS_);

    #pragma unroll
    for (int it = 0; it < 4; ++it) {
        const int n  = it * 256 + t;
        const int ll = n >> 5, d4 = n & 31;
        const size_t idx = (size_t)(b * L_ + sl * 32 + ll) * D_ + h * HD_ + d4 * 4;
        float4 v = *(const float4*)&out[idx];
        const float4 w4 = *(const float4*)&gw[h * HD_ + d4 * 4];
        const float4 b4 = *(const float4*)&gb[h * HD_ + d4 * 4];
        v.x = (v.x - mean) * rstd * w4.x + b4.x;
        v.y = (v.y - mean) * rstd * w4.y + b4.y;
        v.z = (v.z - mean) * rstd * w4.z + b4.z;
        v.w = (v.w - mean) * rstd * w4.w + b4.w;
        *(float4*)&out[idx] = v;
    }
}

// ---------------------------------------------------------------------------
extern "C" void kernel_launch(void* const* d_in, const int* in_sizes, int n_in,
                              void* d_out, int out_size, void* d_ws, size_t ws_size,
                              hipStream_t stream) {
    const float* x  = (const float*)d_in[0];
    const float* Wq = (const float*)d_in[1];
    const float* Wk = (const float*)d_in[2];
    const float* Wv = (const float*)d_in[3];
    const float* gl = (const float*)d_in[4];
    const float* gw = (const float*)d_in[5];
    const float* gb = (const float*)d_in[6];
    float* out = (float*)d_out;

    __hip_bfloat16* ws = (__hip_bfloat16*)d_ws;
    __hip_bfloat16* xb  = ws;                    // 8,388,608 el
    __hip_bfloat16* Wqb = xb  + 8388608;         // 4,194,304 el each (contiguous)
    __hip_bfloat16* Wkb = Wqb + 4194304;
    __hip_bfloat16* Wvb = Wkb + 4194304;
    __hip_bfloat16* Qbf = Wvb + 4194304;         // 8,388,608 el each
    __hip_bfloat16* Kbf = Qbf + 8388608;
    __hip_bfloat16* VTb = Kbf + 8388608;         // V transposed [b,n,l]
    float2* part = (float2*)(VTb + 8388608);     // 512 float2
    __hip_bfloat16* KTb = (__hip_bfloat16*)(part + 512);   // 8,388,608 el

    __hip_bfloat16* SpT = xb;                    // overlay (xb dead after proj)
    __hip_bfloat16* SbT = Wqb;                   // overlay (W dead after proj)

    const int use_chunks = (ws_size >= 109056000ULL) ? 1 : 0;

    cast4_kernel<<<2048, 256, 0, stream>>>(x, Wq, Wk, Wv, xb);

    proj256<<<dim3(384), 512, 0, stream>>>(xb, Wqb, Qbf, Kbf, VTb,
                                           use_chunks ? KTb : nullptr);

    if (use_chunks) {
        state_part<<<dim3(512), 256, 0, stream>>>(KTb, VTb, gl, SpT);
        state_scan<<<dim3(32, 16), 256, 0, stream>>>(SpT, SbT, gl);
    }

    retn_kernel<<<dim3(512), 256, 0, stream>>>(Qbf, Kbf, VTb, gl, out, part,
                                               use_chunks ? SbT : nullptr,
                                               use_chunks);

    gn_apply<<<dim3(32, 64), 256, 0, stream>>>(out, part, gw, gb);
}

// Round 14
// 184.431 us; speedup vs baseline: 1.0870x; 1.0870x over previous
//
#include <hip/hip_runtime.h>
#include <hip/hip_bf16.h>
#include <math.h>

#define B_  2
#define L_  2048
#define D_  2048
#define H_  16
#define HD_ 128
#define EPS_ 1e-5f
#define NTK 32   // K / 64

typedef __attribute__((ext_vector_type(8)))  short short8;
typedef __attribute__((ext_vector_type(4)))  float f32x4;
typedef __attribute__((ext_vector_type(16))) float f32x16;

static __device__ inline unsigned short bfb(float x) {
    __hip_bfloat16 h = __float2bfloat16(x);
    unsigned short s;
    __builtin_memcpy(&s, &h, 2);
    return s;
}
static __device__ inline unsigned pk2(float a, float b) {
    return (unsigned)bfb(a) | ((unsigned)bfb(b) << 16);
}
static __device__ inline float bf2f(unsigned short u) {
    unsigned v = ((unsigned)u) << 16;
    float f;
    __builtin_memcpy(&f, &v, 4);
    return f;
}

// direct-to-LDS 16B copy: LDS dest = wave-uniform base + lane*16
static __device__ __forceinline__ void gld_lds16(const void* g, void* l) {
    __builtin_amdgcn_global_load_lds(
        (const __attribute__((address_space(1))) unsigned int*)g,
        (__attribute__((address_space(3))) unsigned int*)l,
        16, 0, 0);
}

// ---------------------------------------------------------------------------
// fused cast f32 -> bf16 for x, Wq, Wk, Wv (dsts contiguous in ws)
// ---------------------------------------------------------------------------
#define XN4 2097152              // 8388608/4
#define WN4 1048576              // 4194304/4
#define TOT4 (XN4 + 3 * WN4)     // 5242880

__global__ __launch_bounds__(256) void cast4_kernel(
    const float* __restrict__ x,  const float* __restrict__ Wq,
    const float* __restrict__ Wk, const float* __restrict__ Wv,
    __hip_bfloat16* __restrict__ dst)
{
    int i = blockIdx.x * 256 + threadIdx.x;
    const int st = gridDim.x * 256;
    for (; i < TOT4; i += st) {
        const float* s;
        int off;
        if (i < XN4)                { s = x;  off = i; }
        else if (i < XN4 + WN4)     { s = Wq; off = i - XN4; }
        else if (i < XN4 + 2 * WN4) { s = Wk; off = i - XN4 - WN4; }
        else                        { s = Wv; off = i - XN4 - 2 * WN4; }
        float4 v = ((const float4*)s)[off];
        uint2 r;
        r.x = pk2(v.x, v.y);
        r.y = pk2(v.z, v.w);
        ((uint2*)dst)[i] = r;
    }
}

// ---------------------------------------------------------------------------
// Fused projection GEMM (round-10 proven best: 112 us, MfmaUtil 40%).
// BM=128 x BN=256, BK=64, 512 thr / 8 waves (2Mx4N), wave tile 64x64,
// LDS 96KB double-buffered, counted-vmcnt pipeline, rule-21 swizzle,
// XCD-chunked nt-major mapping.  zsel: Q,K -> [b,h,l,hd] (+KT); V -> [b,n,l].
// ---------------------------------------------------------------------------
__global__ __launch_bounds__(512) void proj8(
    const __hip_bfloat16* __restrict__ X,
    const __hip_bfloat16* __restrict__ Wc,
    __hip_bfloat16* __restrict__ Qo, __hip_bfloat16* __restrict__ Ko,
    __hip_bfloat16* __restrict__ VT, __hip_bfloat16* __restrict__ KT)
{
    __shared__ __align__(16) char lds[98304];   // A0|A1 (16K each) + B0|B1 (32K each)

    const int t  = threadIdx.x;
    const int w  = t >> 6, l = t & 63;
    const int li = l & 15, hi4 = l >> 4;
    const int wm = w >> 2, wn = w & 3;

    const int bid = blockIdx.x;
    const int wg  = (bid & 7) * 96 + (bid >> 3);   // XCD-chunked (768 % 8 == 0)
    const int nt  = wg >> 5;                       // 0..23  n-panel major
    const int mt  = wg & 31;                       // 0..31
    const int m0  = mt * 128;
    const int n0g = nt * 256;

    const int srow = l >> 3;                       // row within 8-row chunk
    const int scol = ((l & 7) ^ (l >> 3)) * 8;     // pre-swizzled source col
    const int ca0  = 2 * w;                        // A chunks 2w, 2w+1
    const int cb0  = 4 * w;                        // B chunks 4w..4w+3

    f32x4 acc[4][4];
    #pragma unroll
    for (int i = 0; i < 4; ++i)
        #pragma unroll
        for (int j = 0; j < 4; ++j)
            #pragma unroll
            for (int r = 0; r < 4; ++r) acc[i][j][r] = 0.f;

    auto STAGE_A = [&](int tt) {   // 2 A-chunks + 1 B-chunk
        char* Ab = lds + (tt & 1) * 16384;
        char* Bb = lds + 32768 + (tt & 1) * 32768;
        const size_t kc = (size_t)(tt * 64) + scol;
        gld_lds16(X  + (size_t)(m0 + ca0 * 8 + srow) * D_ + kc,      Ab + ca0 * 1024);
        gld_lds16(X  + (size_t)(m0 + ca0 * 8 + 8 + srow) * D_ + kc,  Ab + ca0 * 1024 + 1024);
        gld_lds16(Wc + (size_t)(n0g + cb0 * 8 + srow) * D_ + kc,     Bb + cb0 * 1024);
    };
    auto STAGE_B = [&](int tt) {   // remaining 3 B-chunks
        char* Bb = lds + 32768 + (tt & 1) * 32768;
        const size_t kc = (size_t)(tt * 64) + scol;
        gld_lds16(Wc + (size_t)(n0g + (cb0 + 1) * 8 + srow) * D_ + kc, Bb + (cb0 + 1) * 1024);
        gld_lds16(Wc + (size_t)(n0g + (cb0 + 2) * 8 + srow) * D_ + kc, Bb + (cb0 + 2) * 1024);
        gld_lds16(Wc + (size_t)(n0g + (cb0 + 3) * 8 + srow) * D_ + kc, Bb + (cb0 + 3) * 1024);
    };

    STAGE_A(0); STAGE_B(0); STAGE_A(1); STAGE_B(1);   // 12 loads in flight

    const int cbk0 = (hi4 * 16) ^ ((li & 7) << 4);        // kk0 read offset
    const int cbk1 = (64 + hi4 * 16) ^ ((li & 7) << 4);   // kk1 read offset

    #pragma unroll 2
    for (int kt = 0; kt < NTK; ++kt) {
        const char* Ab = lds + (kt & 1) * 16384;
        const char* Bb = lds + 32768 + (kt & 1) * 32768;

        if (kt < NTK - 1) asm volatile("s_waitcnt vmcnt(6)" ::: "memory");
        else              asm volatile("s_waitcnt vmcnt(0)" ::: "memory");
        __builtin_amdgcn_s_barrier();

        short8 a0[4], b0[4], a1[4], b1[4];
        #pragma unroll
        for (int mf = 0; mf < 4; ++mf)
            a0[mf] = *(const short8*)(Ab + (wm * 64 + mf * 16 + li) * 128 + cbk0);
        #pragma unroll
        for (int nf = 0; nf < 4; ++nf)
            b0[nf] = *(const short8*)(Bb + (wn * 64 + nf * 16 + li) * 128 + cbk0);
        __builtin_amdgcn_s_setprio(1);
        #pragma unroll
        for (int mf = 0; mf < 4; ++mf)
            #pragma unroll
            for (int nf = 0; nf < 2; ++nf)
                acc[mf][nf] = __builtin_amdgcn_mfma_f32_16x16x32_bf16(
                    a0[mf], b0[nf], acc[mf][nf], 0, 0, 0);
        __builtin_amdgcn_s_setprio(0);

        #pragma unroll
        for (int mf = 0; mf < 4; ++mf)
            a1[mf] = *(const short8*)(Ab + (wm * 64 + mf * 16 + li) * 128 + cbk1);
        #pragma unroll
        for (int nf = 0; nf < 4; ++nf)
            b1[nf] = *(const short8*)(Bb + (wn * 64 + nf * 16 + li) * 128 + cbk1);
        __builtin_amdgcn_s_setprio(1);
        #pragma unroll
        for (int mf = 0; mf < 4; ++mf)
            #pragma unroll
            for (int nf = 2; nf < 4; ++nf)
                acc[mf][nf] = __builtin_amdgcn_mfma_f32_16x16x32_bf16(
                    a0[mf], b0[nf], acc[mf][nf], 0, 0, 0);
        __builtin_amdgcn_s_setprio(0);

        asm volatile("s_waitcnt lgkmcnt(0)" ::: "memory");
        __builtin_amdgcn_s_barrier();

        if (kt < NTK - 2) STAGE_A(kt + 2);
        __builtin_amdgcn_s_setprio(1);
        #pragma unroll
        for (int mf = 0; mf < 4; ++mf)
            #pragma unroll
            for (int nf = 0; nf < 2; ++nf)
                acc[mf][nf] = __builtin_amdgcn_mfma_f32_16x16x32_bf16(
                    a1[mf], b1[nf], acc[mf][nf], 0, 0, 0);
        __builtin_amdgcn_s_setprio(0);

        if (kt < NTK - 2) STAGE_B(kt + 2);
        __builtin_amdgcn_s_setprio(1);
        #pragma unroll
        for (int mf = 0; mf < 4; ++mf)
            #pragma unroll
            for (int nf = 2; nf < 4; ++nf)
                acc[mf][nf] = __builtin_amdgcn_mfma_f32_16x16x32_bf16(
                    a1[mf], b1[nf], acc[mf][nf], 0, 0, 0);
        __builtin_amdgcn_s_setprio(0);
    }

    // epilogue: C[r]: row = hi4*4 + r, col = li (within 16x16 frag)
    const int zsel = n0g >> 11;
    const int np   = n0g & (D_ - 1);
    if (zsel == 2) {
        #pragma unroll
        for (int mf = 0; mf < 4; ++mf) {
            #pragma unroll
            for (int nf = 0; nf < 4; ++nf) {
                const int n     = np + wn * 64 + nf * 16 + li;
                const int mbase = m0 + wm * 64 + mf * 16 + hi4 * 4;
                const int b = mbase >> 11, ml = mbase & (L_ - 1);
                uint2 w2;
                w2.x = pk2(acc[mf][nf][0], acc[mf][nf][1]);
                w2.y = pk2(acc[mf][nf][2], acc[mf][nf][3]);
                *(uint2*)&VT[((size_t)b * D_ + n) * L_ + ml] = w2;
            }
        }
    } else {
        __hip_bfloat16* O = zsel ? Ko : Qo;
        #pragma unroll
        for (int mf = 0; mf < 4; ++mf) {
            #pragma unroll
            for (int nf = 0; nf < 4; ++nf) {
                const int n  = np + wn * 64 + nf * 16 + li;
                const int h  = n >> 7, hd = n & (HD_ - 1);
                #pragma unroll
                for (int r = 0; r < 4; ++r) {
                    const int m = m0 + wm * 64 + mf * 16 + hi4 * 4 + r;
                    const int b = m >> 11, ml = m & (L_ - 1);
                    O[((size_t)(b * H_ + h) * L_ + ml) * HD_ + hd] =
                        __float2bfloat16(acc[mf][nf][r]);
                }
            }
        }
        if (zsel == 1 && KT != nullptr) {
            #pragma unroll
            for (int mf = 0; mf < 4; ++mf) {
                #pragma unroll
                for (int nf = 0; nf < 4; ++nf) {
                    const int n     = np + wn * 64 + nf * 16 + li;
                    const int mbase = m0 + wm * 64 + mf * 16 + hi4 * 4;
                    const int b = mbase >> 11, ml = mbase & (L_ - 1);
                    uint2 w2;
                    w2.x = pk2(acc[mf][nf][0], acc[mf][nf][1]);
                    w2.y = pk2(acc[mf][nf][2], acc[mf][nf][3]);
                    *(uint2*)&KT[((size_t)b * D_ + n) * L_ + ml] = w2;
                }
            }
        }
    }
}

// ---------------------------------------------------------------------------
// State partials: SpT[bh][c][d][k] = sum_{j in chunk c} gamma^(127-j_loc) V[j,d] K[j,k]
// ---------------------------------------------------------------------------
__global__ __launch_bounds__(256) void state_part(
    const __hip_bfloat16* __restrict__ KT, const __hip_bfloat16* __restrict__ VT,
    const float* __restrict__ gl, __hip_bfloat16* __restrict__ SpT)
{
    const int bid = blockIdx.x;       // 512 = c*32 + bh
    const int bh  = bid & 31, c = bid >> 5;
    const int h   = bh & (H_ - 1);
    const int t   = threadIdx.x;
    const int w   = t >> 6, l = t & 63;
    const int li  = l & 31, hi = l >> 5;

    const float gamma = 1.f / (1.f + __expf(-gl[h]));
    const float lg2   = __log2f(gamma);

    __shared__ __align__(16) char Kl[32768];
    __shared__ __align__(16) char Vl[32768];

    const __hip_bfloat16* KTg = KT + (size_t)bh * (HD_ * L_);
    const __hip_bfloat16* VTg = VT + (size_t)bh * (HD_ * L_);
    const int gj = c * 128;
    const int srow4 = l >> 4, sslot = l & 15;

    #pragma unroll
    for (int cc = 0; cc < 8; ++cc) {
        const int ch = w * 8 + cc;
        const int r  = ch * 4 + srow4;
        const int sc = ((sslot ^ (r & 15)) * 8);
        gld_lds16(KTg + (size_t)r * L_ + gj + sc, Kl + ch * 1024);
        gld_lds16(VTg + (size_t)r * L_ + gj + sc, Vl + ch * 1024);
    }
    __syncthreads();

    f32x16 acc[4];
    #pragma unroll
    for (int cch = 0; cch < 4; ++cch)
        #pragma unroll
        for (int r = 0; r < 16; ++r) acc[cch][r] = 0.f;

    #pragma unroll
    for (int s = 0; s < 8; ++s) {
        const int boff = ((s * 2 + hi) ^ (li & 15)) << 4;
        short8 vraw = *(const short8*)(Vl + (w * 32 + li) * 256 + boff);
        short8 af;
        #pragma unroll
        for (int e = 0; e < 8; ++e) {
            const int jl = s * 16 + hi * 8 + e;
            const float f = bf2f((unsigned short)vraw[e]) *
                            exp2f(lg2 * (float)(127 - jl));
            af[e] = (short)bfb(f);
        }
        #pragma unroll
        for (int cch = 0; cch < 4; ++cch) {
            short8 bf = *(const short8*)(Kl + (cch * 32 + li) * 256 + boff);
            acc[cch] = __builtin_amdgcn_mfma_f32_32x32x16_bf16(af, bf, acc[cch], 0, 0, 0);
        }
    }

    __hip_bfloat16* Sp = SpT + (size_t)(bh * 16 + c) * 16384;
    #pragma unroll
    for (int cch = 0; cch < 4; ++cch)
        #pragma unroll
        for (int r = 0; r < 16; ++r) {
            const int d = w * 32 + (r & 3) + 8 * (r >> 2) + 4 * hi;
            Sp[(size_t)d * 128 + cch * 32 + li] = __float2bfloat16(acc[cch][r]);
        }
}

// ---------------------------------------------------------------------------
// State scan: S_c = gamma^128 * S_{c-1} + Sp_c
// ---------------------------------------------------------------------------
__global__ __launch_bounds__(256) void state_scan(
    const __hip_bfloat16* __restrict__ SpT, __hip_bfloat16* __restrict__ SbT,
    const float* __restrict__ gl)
{
    const int bh = blockIdx.x;
    const int h  = bh & (H_ - 1);
    const float gamma = 1.f / (1.f + __expf(-gl[h]));
    const float g128  = exp2f(__log2f(gamma) * 128.f);
    const int fid = blockIdx.y * 256 + threadIdx.x;

    float a0 = 0.f, a1 = 0.f, a2 = 0.f, a3 = 0.f;
    for (int c = 0; c < 16; ++c) {
        const size_t off = (size_t)(bh * 16 + c) * 16384 + (size_t)fid * 4;
        uint2 v = *(const uint2*)(SpT + off);
        a0 = g128 * a0 + bf2f((unsigned short)(v.x & 0xffff));
        a1 = g128 * a1 + bf2f((unsigned short)(v.x >> 16));
        a2 = g128 * a2 + bf2f((unsigned short)(v.y & 0xffff));
        a3 = g128 * a3 + bf2f((unsigned short)(v.y >> 16));
        uint2 o;
        o.x = pk2(a0, a1);
        o.y = pk2(a2, a3);
        *(uint2*)(SbT + off) = o;
    }
}

// ---------------------------------------------------------------------------
// Retention (bf16 MFMA), chunked + fallback, fused GN partials.
// ---------------------------------------------------------------------------
__global__ __launch_bounds__(256) void retn_kernel(
    const __hip_bfloat16* __restrict__ Qb, const __hip_bfloat16* __restrict__ Kb,
    const __hip_bfloat16* __restrict__ VT, const float* __restrict__ gl,
    float* __restrict__ out, float2* __restrict__ part,
    const __hip_bfloat16* __restrict__ SbT, int use_chunks)
{
    const int bid = blockIdx.x;
    const int mm  = bid >> 5;
    const int m   = use_chunks ? mm : ((mm < 8) ? (15 - mm) : (mm - 8));
    const int bh  = bid & 31;
    const int b   = bh >> 4, h = bh & (H_ - 1);
    const int t   = threadIdx.x;
    const int w   = t >> 6, l = t & 63;
    const int li  = l & 31, hi = l >> 5;

    const float gamma = 1.f / (1.f + __expf(-gl[h]));
    const float lg2   = __log2f(gamma);
    const float scale = 0.08838834764831845f;   // 128^-0.5

    __shared__ __align__(16) char Klds[32768];
    __shared__ __align__(16) char Vlds[32768];
    __shared__ float rs[4], rq[4];

    const size_t base = (size_t)bh * (L_ * HD_);
    const __hip_bfloat16* VTg = VT + (size_t)bh * (HD_ * L_);
    const int i0 = m * 128 + w * 32;

    short8 qf[8];
    {
        const __hip_bfloat16* qrow = Qb + base + (size_t)(i0 + li) * HD_;
        #pragma unroll
        for (int s = 0; s < 8; ++s)
            qf[s] = *(const short8*)(qrow + s * 16 + hi * 8);
    }

    float df[16];
    #pragma unroll
    for (int r = 0; r < 16; ++r) {
        const int jl = (r & 3) + 8 * (r >> 2) + 4 * hi;
        df[r] = exp2f(lg2 * (float)(li - jl));
    }

    f32x16 acc[4];
    #pragma unroll
    for (int c = 0; c < 4; ++c)
        #pragma unroll
        for (int r = 0; r < 16; ++r) acc[c][r] = 0.f;

    const int srow4 = l >> 4;
    const int sslot = l & 15;

    if (use_chunks && m > 0) {
        const __hip_bfloat16* Sg = SbT + (size_t)(bh * 16 + (m - 1)) * 16384;
        #pragma unroll
        for (int cc = 0; cc < 8; ++cc) {
            const int ch = w * 8 + cc;
            const int r  = ch * 4 + srow4;
            const int sc = ((sslot ^ (r & 15)) * 8);
            gld_lds16(Sg + (size_t)r * 128 + sc, Klds + ch * 1024);
        }
        __syncthreads();
        #pragma unroll
        for (int s = 0; s < 8; ++s) {
            const int boff = ((s * 2 + hi) ^ (li & 15)) << 4;
            #pragma unroll
            for (int cch = 0; cch < 4; ++cch) {
                short8 sf = *(const short8*)(Klds + (cch * 32 + li) * 256 + boff);
                acc[cch] = __builtin_amdgcn_mfma_f32_32x32x16_bf16(
                    qf[s], sf, acc[cch], 0, 0, 0);
            }
        }
        #pragma unroll
        for (int r = 0; r < 16; ++r) {
            const int il = (r & 3) + 8 * (r >> 2) + 4 * hi + w * 32;
            const float fr = exp2f(lg2 * (float)(il + 1)) * scale;
            acc[0][r] *= fr; acc[1][r] *= fr; acc[2][r] *= fr; acc[3][r] *= fr;
        }
    }

    const int gj0 = use_chunks ? m * 128 : 0;
    for (int gj = gj0; gj <= m * 128; gj += 128) {
        __syncthreads();
        #pragma unroll
        for (int cc = 0; cc < 8; ++cc) {
            const int c  = w * 8 + cc;
            const int r  = c * 4 + srow4;
            const int sc = ((sslot ^ (r & 15)) * 8);
            gld_lds16(Kb + base + (size_t)(gj + r) * HD_ + sc, Klds + c * 1024);
            gld_lds16(VTg + (size_t)r * L_ + gj + sc,          Vlds + c * 1024);
        }
        __syncthreads();

        const int tmax = ((i0 - gj) >> 5) < 3 ? ((i0 - gj) >> 5) : 3;
        for (int jt = 0; jt <= tmax; ++jt) {
            const int j0 = gj + jt * 32;

            f32x16 c;
            #pragma unroll
            for (int r = 0; r < 16; ++r) c[r] = 0.f;
            #pragma unroll
            for (int s = 0; s < 8; ++s) {
                short8 kf = *(const short8*)(Klds + (jt * 32 + li) * 256 +
                                             (((s * 2 + hi) ^ (li & 15)) << 4));
                c = __builtin_amdgcn_mfma_f32_32x32x16_bf16(kf, qf[s], c, 0, 0, 0);
            }

            float p[16];
            const float bt = exp2f(lg2 * (float)(i0 - j0)) * scale;
            if (j0 == i0) {
                #pragma unroll
                for (int r = 0; r < 16; ++r) {
                    const int jl = (r & 3) + 8 * (r >> 2) + 4 * hi;
                    p[r] = (jl <= li) ? c[r] * (df[r] * bt) : 0.f;
                }
            } else {
                #pragma unroll
                for (int r = 0; r < 16; ++r) p[r] = c[r] * (df[r] * bt);
            }

            #pragma unroll
            for (int sl = 0; sl < 2; ++sl) {
                const int o = sl * 8;
                unsigned pk01 = pk2(p[o + 0], p[o + 1]);
                unsigned pk23 = pk2(p[o + 2], p[o + 3]);
                unsigned pk45 = pk2(p[o + 4], p[o + 5]);
                unsigned pk67 = pk2(p[o + 6], p[o + 7]);
                unsigned x01 = (unsigned)__shfl_xor((int)pk01, 32);
                unsigned x23 = (unsigned)__shfl_xor((int)pk23, 32);
                unsigned x45 = (unsigned)__shfl_xor((int)pk45, 32);
                unsigned x67 = (unsigned)__shfl_xor((int)pk67, 32);
                union { short8 v; unsigned u[4]; } pf;
                pf.u[0] = hi ? x45 : pk01;
                pf.u[1] = hi ? x67 : pk23;
                pf.u[2] = hi ? pk45 : x01;
                pf.u[3] = hi ? pk67 : x23;
                #pragma unroll
                for (int cch = 0; cch < 4; ++cch) {
                    short8 vf = *(const short8*)(Vlds + (cch * 32 + li) * 256 +
                                 (((jt * 4 + sl * 2 + hi) ^ (li & 15)) << 4));
                    acc[cch] = __builtin_amdgcn_mfma_f32_32x32x16_bf16(
                        pf.v, vf, acc[cch], 0, 0, 0);
                }
            }
        }
    }

    float s = 0.f, sq = 0.f;
    #pragma unroll
    for (int cch = 0; cch < 4; ++cch) {
        #pragma unroll
        for (int r = 0; r < 16; ++r) {
            const int row = (r & 3) + 8 * (r >> 2) + 4 * hi;
            const float v = acc[cch][r];
            out[(size_t)(b * L_ + i0 + row) * D_ + h * HD_ + cch * 32 + li] = v;
            s += v; sq += v * v;
        }
    }

    #pragma unroll
    for (int off = 32; off > 0; off >>= 1) {
        s  += __shfl_down(s, off);
        sq += __shfl_down(sq, off);
    }
    if (l == 0) { rs[w] = s; rq[w] = sq; }
    __syncthreads();
    if (t == 0)
        part[bh * 16 + m] = make_float2(rs[0] + rs[1] + rs[2] + rs[3],
                                        rq[0] + rq[1] + rq[2] + rq[3]);
}

// ---------------------------------------------------------------------------
// GroupNorm apply (stats partials come fused from retn_kernel)
// ---------------------------------------------------------------------------
__global__ __launch_bounds__(256) void gn_apply(
    float* __restrict__ out, const float2* __restrict__ part,
    const float* __restrict__ gw, const float* __restrict__ gb)
{
    const int bh = blockIdx.x, sl = blockIdx.y;
    const int b = bh >> 4, h = bh & (H_ - 1);
    const int t = threadIdx.x;

    float S = 0.f, SQ = 0.f;
    #pragma unroll
    for (int i = 0; i < 16; ++i) {
        float2 p = part[bh * 16 + i];
        S += p.x; SQ += p.y;
    }
    const float inv  = 1.f / (float)(L_ * HD_);
    const float mean = S * inv;
    float var = SQ * inv - mean * mean;
    if (var < 0.f) var = 0.f;
    const float rstd = rsqrtf(var + EPS_);

    #pragma unroll
    for (int it = 0; it < 4; ++it) {
        const int n  = it * 256 + t;
        const int ll = n >> 5, d4 = n & 31;
        const size_t idx = (size_t)(b * L_ + sl * 32 + ll) * D_ + h * HD_ + d4 * 4;
        float4 v = *(const float4*)&out[idx];
        const float4 w4 = *(const float4*)&gw[h * HD_ + d4 * 4];
        const float4 b4 = *(const float4*)&gb[h * HD_ + d4 * 4];
        v.x = (v.x - mean) * rstd * w4.x + b4.x;
        v.y = (v.y - mean) * rstd * w4.y + b4.y;
        v.z = (v.z - mean) * rstd * w4.z + b4.z;
        v.w = (v.w - mean) * rstd * w4.w + b4.w;
        *(float4*)&out[idx] = v;
    }
}

// ---------------------------------------------------------------------------
extern "C" void kernel_launch(void* const* d_in, const int* in_sizes, int n_in,
                              void* d_out, int out_size, void* d_ws, size_t ws_size,
                              hipStream_t stream) {
    const float* x  = (const float*)d_in[0];
    const float* Wq = (const float*)d_in[1];
    const float* Wk = (const float*)d_in[2];
    const float* Wv = (const float*)d_in[3];
    const float* gl = (const float*)d_in[4];
    const float* gw = (const float*)d_in[5];
    const float* gb = (const float*)d_in[6];
    float* out = (float*)d_out;

    __hip_bfloat16* ws = (__hip_bfloat16*)d_ws;
    __hip_bfloat16* xb  = ws;                    // 8,388,608 el
    __hip_bfloat16* Wqb = xb  + 8388608;         // 4,194,304 el each (contiguous)
    __hip_bfloat16* Wkb = Wqb + 4194304;
    __hip_bfloat16* Wvb = Wkb + 4194304;
    __hip_bfloat16* Qbf = Wvb + 4194304;         // 8,388,608 el each
    __hip_bfloat16* Kbf = Qbf + 8388608;
    __hip_bfloat16* VTb = Kbf + 8388608;         // V transposed [b,n,l]
    float2* part = (float2*)(VTb + 8388608);     // 512 float2
    __hip_bfloat16* KTb = (__hip_bfloat16*)(part + 512);   // 8,388,608 el

    __hip_bfloat16* SpT = xb;                    // overlay (xb dead after proj)
    __hip_bfloat16* SbT = Wqb;                   // overlay (W dead after proj)

    const int use_chunks = (ws_size >= 109056000ULL) ? 1 : 0;

    cast4_kernel<<<2048, 256, 0, stream>>>(x, Wq, Wk, Wv, xb);

    proj8<<<dim3(768), 512, 0, stream>>>(xb, Wqb, Qbf, Kbf, VTb,
                                         use_chunks ? KTb : nullptr);

    if (use_chunks) {
        state_part<<<dim3(512), 256, 0, stream>>>(KTb, VTb, gl, SpT);
        state_scan<<<dim3(32, 16), 256, 0, stream>>>(SpT, SbT, gl);
    }

    retn_kernel<<<dim3(512), 256, 0, stream>>>(Qbf, Kbf, VTb, gl, out, part,
                                               use_chunks ? SbT : nullptr,
                                               use_chunks);

    gn_apply<<<dim3(32, 64), 256, 0, stream>>>(out, part, gw, gb);
}